// Round 2
// baseline (1106.656 us; speedup 1.0000x reference)
//
#include <hip/hip_runtime.h>
#include <hip/hip_bf16.h>
#include <math.h>

#define D_DIM 768
#define B_DIM 64
#define L_DIM 512
#define M_DIM (B_DIM * L_DIM)   /* 32768 rows */
#define YD 3
#define ZD 5
#define LN_EPS 1e-5f
#define COS_EPS 1e-8f

// ---------------------------------------------------------------------------
// GEMM: out[M,768] = epilogue( A[M,768] @ W[768,768] + bias )
// MODE 0: out = relu(acc + bias)                      (h1)
// MODE 1: out = acc + bias + resid                    (x = emb + h2)
// 128x128 tile, BK=32, 256 threads, 8x8 micro-tile per thread. fp32 vector FMA
// (no fp32 MFMA on CDNA4).
// ---------------------------------------------------------------------------
template<int MODE>
__global__ __launch_bounds__(256, 2)
void gemm768(const float* __restrict__ A, const float* __restrict__ W,
             const float* __restrict__ bias, const float* __restrict__ resid,
             float* __restrict__ out)
{
    constexpr int BM = 128, BN = 128, BK = 32;
    constexpr int LDA = BM + 4;              // 132 floats: 16B-aligned, ~2-way-free pad
    __shared__ float As[BK][LDA];            // A stored transposed: As[k][m]
    __shared__ float Bs[BK][BN];

    const int t  = threadIdx.x;
    const int tx = t & 15;                   // n-dim 0..15
    const int ty = t >> 4;                   // m-dim 0..15
    const int m0 = blockIdx.y * BM;
    const int n0 = blockIdx.x * BN;

    float acc[8][8];
    #pragma unroll
    for (int j = 0; j < 8; ++j)
        #pragma unroll
        for (int i = 0; i < 8; ++i) acc[j][i] = 0.f;

    const int arow = t >> 3;                 // 0..31
    const int acol = (t & 7) * 4;            // 0..28
    const int brow = t >> 5;                 // 0..7
    const int bcol = (t & 31) * 4;           // 0..124

    for (int kk = 0; kk < D_DIM; kk += BK) {
        #pragma unroll
        for (int i = 0; i < 4; ++i) {
            const float4 av = *reinterpret_cast<const float4*>(
                &A[(size_t)(m0 + arow + i * 32) * D_DIM + kk + acol]);
            As[acol + 0][arow + i * 32] = av.x;
            As[acol + 1][arow + i * 32] = av.y;
            As[acol + 2][arow + i * 32] = av.z;
            As[acol + 3][arow + i * 32] = av.w;
            *reinterpret_cast<float4*>(&Bs[brow + i * 8][bcol]) =
                *reinterpret_cast<const float4*>(
                    &W[(size_t)(kk + brow + i * 8) * D_DIM + n0 + bcol]);
        }
        __syncthreads();
        #pragma unroll 8
        for (int k = 0; k < BK; ++k) {
            float a[8], b[8];
            *reinterpret_cast<float4*>(&a[0]) = *reinterpret_cast<const float4*>(&As[k][ty * 4]);
            *reinterpret_cast<float4*>(&a[4]) = *reinterpret_cast<const float4*>(&As[k][64 + ty * 4]);
            *reinterpret_cast<float4*>(&b[0]) = *reinterpret_cast<const float4*>(&Bs[k][tx * 4]);
            *reinterpret_cast<float4*>(&b[4]) = *reinterpret_cast<const float4*>(&Bs[k][64 + tx * 4]);
            #pragma unroll
            for (int j = 0; j < 8; ++j)
                #pragma unroll
                for (int i = 0; i < 8; ++i)
                    acc[j][i] = fmaf(a[j], b[i], acc[j][i]);
        }
        __syncthreads();
    }

    #pragma unroll
    for (int j = 0; j < 8; ++j) {
        const int mloc = (j < 4) ? (ty * 4 + j) : (64 + ty * 4 + (j - 4));
        const size_t rowoff = (size_t)(m0 + mloc) * D_DIM;
        #pragma unroll
        for (int half = 0; half < 2; ++half) {
            const int ncol = n0 + half * 64 + tx * 4;
            const float4 bv = *reinterpret_cast<const float4*>(&bias[ncol]);
            float4 o;
            o.x = acc[j][half * 4 + 0] + bv.x;
            o.y = acc[j][half * 4 + 1] + bv.y;
            o.z = acc[j][half * 4 + 2] + bv.z;
            o.w = acc[j][half * 4 + 3] + bv.w;
            if (MODE == 0) {
                o.x = fmaxf(o.x, 0.f); o.y = fmaxf(o.y, 0.f);
                o.z = fmaxf(o.z, 0.f); o.w = fmaxf(o.w, 0.f);
            } else {
                const float4 rv = *reinterpret_cast<const float4*>(&resid[rowoff + ncol]);
                o.x += rv.x; o.y += rv.y; o.z += rv.z; o.w += rv.w;
            }
            *reinterpret_cast<float4*>(&out[rowoff + ncol]) = o;
        }
    }
}

// ---------------------------------------------------------------------------
// LayerNorm in-place over each row of x[M,768]; also writes rnorm[m] =
// 1/max(||ff_row||, COS_EPS). One wave per row, 4 rows per block.
// ---------------------------------------------------------------------------
__global__ __launch_bounds__(256)
void ln_kernel(float* __restrict__ x, const float* __restrict__ gamma,
               const float* __restrict__ beta, float* __restrict__ rnorm)
{
    const int wave = threadIdx.x >> 6;
    const int lane = threadIdx.x & 63;
    const int row  = blockIdx.x * 4 + wave;
    float* xr = x + (size_t)row * D_DIM;

    float v[12];
    float sum = 0.f, sumsq = 0.f;
    #pragma unroll
    for (int j = 0; j < 3; ++j) {
        const float4 f = *reinterpret_cast<const float4*>(&xr[j * 256 + lane * 4]);
        v[j * 4 + 0] = f.x; v[j * 4 + 1] = f.y; v[j * 4 + 2] = f.z; v[j * 4 + 3] = f.w;
    }
    #pragma unroll
    for (int e = 0; e < 12; ++e) { sum += v[e]; sumsq = fmaf(v[e], v[e], sumsq); }
    #pragma unroll
    for (int m = 1; m < 64; m <<= 1) {
        sum   += __shfl_xor(sum, m);
        sumsq += __shfl_xor(sumsq, m);
    }
    const float mean = sum * (1.f / 768.f);
    const float var  = sumsq * (1.f / 768.f) - mean * mean;
    const float rstd = 1.f / sqrtf(var + LN_EPS);

    float nsq = 0.f;
    #pragma unroll
    for (int j = 0; j < 3; ++j) {
        const int c = j * 256 + lane * 4;
        const float4 g  = *reinterpret_cast<const float4*>(&gamma[c]);
        const float4 bt = *reinterpret_cast<const float4*>(&beta[c]);
        float4 o;
        o.x = fmaf(g.x * (v[j*4+0] - mean), rstd, bt.x);
        o.y = fmaf(g.y * (v[j*4+1] - mean), rstd, bt.y);
        o.z = fmaf(g.z * (v[j*4+2] - mean), rstd, bt.z);
        o.w = fmaf(g.w * (v[j*4+3] - mean), rstd, bt.w);
        nsq = fmaf(o.x, o.x, nsq); nsq = fmaf(o.y, o.y, nsq);
        nsq = fmaf(o.z, o.z, nsq); nsq = fmaf(o.w, o.w, nsq);
        *reinterpret_cast<float4*>(&xr[c]) = o;
    }
    #pragma unroll
    for (int m = 1; m < 64; m <<= 1) nsq += __shfl_xor(nsq, m);
    if (lane == 0) rnorm[row] = 1.f / fmaxf(sqrtf(nsq), COS_EPS);
}

// ---------------------------------------------------------------------------
// zero-init for s[B*D] (replaces hipMemsetAsync — keeps kernel_launch
// pure-kernel for graph capture safety)
// ---------------------------------------------------------------------------
__global__ void zero_kernel(float* __restrict__ p, int n)
{
    const int i = blockIdx.x * 256 + threadIdx.x;
    if (i < n) p[i] = 0.f;
}

// ---------------------------------------------------------------------------
// s[b][d] = sum_l ff[b][l][d] * rnorm[b][l]   (partial over L-quarters, atomic)
// grid (3 d-chunks, 4 l-quarters, 64 b), 256 threads
// ---------------------------------------------------------------------------
__global__ __launch_bounds__(256)
void colsum_kernel(const float* __restrict__ ff, const float* __restrict__ rnorm,
                   float* __restrict__ s)
{
    const int c = blockIdx.x * 256 + threadIdx.x;
    const int q = blockIdx.y;
    const int b = blockIdx.z;
    const float* fb = ff + (size_t)b * L_DIM * D_DIM;
    const float* rb = rnorm + b * L_DIM;
    float acc = 0.f;
    #pragma unroll 4
    for (int l = q * 128; l < q * 128 + 128; ++l)
        acc = fmaf(fb[(size_t)l * D_DIM + c], rb[l], acc);
    atomicAdd(&s[b * D_DIM + c], acc);
}

// ---------------------------------------------------------------------------
// Per-row epilogue: out1 = ff@Wy + by, out2 = ff@Wz + bz,
// aw_raw = 1/(1+exp(ff.s * rnorm / L)). One wave per row.
// ---------------------------------------------------------------------------
__global__ __launch_bounds__(256)
void rowout_kernel(const float* __restrict__ ff, const float* __restrict__ rnorm,
                   const float* __restrict__ s,
                   const float* __restrict__ Wy, const float* __restrict__ by,
                   const float* __restrict__ Wz, const float* __restrict__ bz,
                   float* __restrict__ out1, float* __restrict__ out2,
                   float* __restrict__ aw)
{
    const int wave = threadIdx.x >> 6;
    const int lane = threadIdx.x & 63;
    const int row  = blockIdx.x * 4 + wave;
    const int b    = row >> 9;
    const float* fr = ff + (size_t)row * D_DIM;
    const float* sb = s + b * D_DIM;

    float ds = 0.f;
    float dy[YD] = {0.f, 0.f, 0.f};
    float dz[ZD] = {0.f, 0.f, 0.f, 0.f, 0.f};
    #pragma unroll
    for (int j = 0; j < 3; ++j) {
        const int c = j * 256 + lane * 4;
        const float4 f  = *reinterpret_cast<const float4*>(&fr[c]);
        const float4 sv = *reinterpret_cast<const float4*>(&sb[c]);
        const float fe[4] = {f.x, f.y, f.z, f.w};
        const float se[4] = {sv.x, sv.y, sv.z, sv.w};
        #pragma unroll
        for (int e = 0; e < 4; ++e) {
            const int col = c + e;
            ds = fmaf(fe[e], se[e], ds);
            #pragma unroll
            for (int y = 0; y < YD; ++y) dy[y] = fmaf(fe[e], Wy[col * YD + y], dy[y]);
            #pragma unroll
            for (int z = 0; z < ZD; ++z) dz[z] = fmaf(fe[e], Wz[col * ZD + z], dz[z]);
        }
    }
    #pragma unroll
    for (int m = 1; m < 64; m <<= 1) {
        ds += __shfl_xor(ds, m);
        #pragma unroll
        for (int y = 0; y < YD; ++y) dy[y] += __shfl_xor(dy[y], m);
        #pragma unroll
        for (int z = 0; z < ZD; ++z) dz[z] += __shfl_xor(dz[z], m);
    }
    if (lane == 0) {
        const float a = ds * rnorm[row] * (1.f / (float)L_DIM);
        aw[row] = 1.f / (1.f + expf(a));
        #pragma unroll
        for (int y = 0; y < YD; ++y) out1[(size_t)row * YD + y] = dy[y] + by[y];
        #pragma unroll
        for (int z = 0; z < ZD; ++z) out2[(size_t)row * ZD + z] = dz[z] + bz[z];
    }
}

// ---------------------------------------------------------------------------
// softmax over L=512 per b of aw (already anti-sigmoided). One block per b.
// ---------------------------------------------------------------------------
__global__ __launch_bounds__(512)
void softmax_kernel(const float* __restrict__ aw, float* __restrict__ attn)
{
    __shared__ float red[8];
    const int b = blockIdx.x;
    const int t = threadIdx.x;
    const int wave = t >> 6, lane = t & 63;
    const float v = aw[b * L_DIM + t];

    float mx = v;
    #pragma unroll
    for (int m = 1; m < 64; m <<= 1) mx = fmaxf(mx, __shfl_xor(mx, m));
    if (lane == 0) red[wave] = mx;
    __syncthreads();
    mx = red[0];
    #pragma unroll
    for (int w = 1; w < 8; ++w) mx = fmaxf(mx, red[w]);
    __syncthreads();

    const float e = expf(v - mx);
    float sm = e;
    #pragma unroll
    for (int m = 1; m < 64; m <<= 1) sm += __shfl_xor(sm, m);
    if (lane == 0) red[wave] = sm;
    __syncthreads();
    float tot = 0.f;
    #pragma unroll
    for (int w = 0; w < 8; ++w) tot += red[w];

    attn[b * L_DIM + t] = e / tot;
}

// ---------------------------------------------------------------------------
extern "C" void kernel_launch(void* const* d_in, const int* in_sizes, int n_in,
                              void* d_out, int out_size, void* d_ws, size_t ws_size,
                              hipStream_t stream)
{
    const float* emb   = (const float*)d_in[0];
    const float* W1    = (const float*)d_in[1];
    const float* b1    = (const float*)d_in[2];
    const float* W2    = (const float*)d_in[3];
    const float* b2    = (const float*)d_in[4];
    const float* gamma = (const float*)d_in[5];
    const float* beta  = (const float*)d_in[6];
    const float* Wy    = (const float*)d_in[7];
    const float* by    = (const float*)d_in[8];
    const float* Wz    = (const float*)d_in[9];
    const float* bz    = (const float*)d_in[10];

    float* out  = (float*)d_out;
    float* ws   = (float*)d_ws;

    float* h1    = ws;                                   // M*D
    float* xf    = h1 + (size_t)M_DIM * D_DIM;           // M*D (x -> ff in place)
    float* rnorm = xf + (size_t)M_DIM * D_DIM;           // M
    float* awb   = rnorm + M_DIM;                        // M
    float* s     = awb + M_DIM;                          // B*D

    float* out1 = out;
    float* out2 = out + (size_t)M_DIM * YD;
    float* attn = out + (size_t)M_DIM * (YD + ZD);

    const dim3 gemm_grid(D_DIM / 128, M_DIM / 128);      // (6, 256)
    gemm768<0><<<gemm_grid, 256, 0, stream>>>(emb, W1, b1, nullptr, h1);
    gemm768<1><<<gemm_grid, 256, 0, stream>>>(h1, W2, b2, emb, xf);
    ln_kernel<<<M_DIM / 4, 256, 0, stream>>>(xf, gamma, beta, rnorm);
    zero_kernel<<<(B_DIM * D_DIM + 255) / 256, 256, 0, stream>>>(s, B_DIM * D_DIM);
    colsum_kernel<<<dim3(3, 4, B_DIM), 256, 0, stream>>>(xf, rnorm, s);
    rowout_kernel<<<M_DIM / 4, 256, 0, stream>>>(xf, rnorm, s, Wy, by, Wz, bz,
                                                 out1, out2, awb);
    softmax_kernel<<<B_DIM, 512, 0, stream>>>(awb, attn);
}

// Round 3
// 582.183 us; speedup vs baseline: 1.9009x; 1.9009x over previous
//
#include <hip/hip_runtime.h>
#include <hip/hip_bf16.h>
#include <math.h>

#define D_DIM 768
#define B_DIM 64
#define L_DIM 512
#define M_DIM (B_DIM * L_DIM)   /* 32768 rows */
#define YD 3
#define ZD 5
#define LN_EPS 1e-5f
#define COS_EPS 1e-8f

typedef short short8v __attribute__((ext_vector_type(8)));
typedef float f32x4  __attribute__((ext_vector_type(4)));

// ---------------------------------------------------------------------------
// bf16 helpers (RNE), split x = hi + lo with hi,lo bf16; |err| <= 2^-17 |x|
// ---------------------------------------------------------------------------
__device__ __forceinline__ unsigned short f2bf(float f) {
    unsigned u = __builtin_bit_cast(unsigned, f);
    u = (u + 0x7fffu + ((u >> 16) & 1u)) >> 16;
    return (unsigned short)u;
}
__device__ __forceinline__ float bf2f(unsigned short h) {
    unsigned u = ((unsigned)h) << 16;
    return __builtin_bit_cast(float, u);
}
__device__ __forceinline__ void split2(float v, unsigned short& h, unsigned short& l) {
    h = f2bf(v);
    l = f2bf(v - bf2f(h));
}

// async global->LDS, 16B per lane, wave-uniform LDS base + lane*16
__device__ __forceinline__ void gld16(const void* g, void* l) {
    __builtin_amdgcn_global_load_lds(
        (const __attribute__((address_space(1))) void*)g,
        (__attribute__((address_space(3))) void*)l, 16, 0, 0);
}

// ---------------------------------------------------------------------------
// split emb -> hi/lo bf16 (vectorized, 4 elems/thread)
// ---------------------------------------------------------------------------
__global__ __launch_bounds__(256)
void split_kernel(const float* __restrict__ in, unsigned short* __restrict__ hi,
                  unsigned short* __restrict__ lo, int n4)
{
    const int i = blockIdx.x * 256 + threadIdx.x;
    if (i >= n4) return;
    const float4 v = reinterpret_cast<const float4*>(in)[i];
    ushort4 h, l;
    split2(v.x, h.x, l.x); split2(v.y, h.y, l.y);
    split2(v.z, h.z, l.z); split2(v.w, h.w, l.w);
    reinterpret_cast<ushort4*>(hi)[i] = h;
    reinterpret_cast<ushort4*>(lo)[i] = l;
}

// ---------------------------------------------------------------------------
// W[768][768] -> Wt_hi/Wt_lo[n][k] (transposed, split). 32x32 LDS tiles.
// ---------------------------------------------------------------------------
__global__ __launch_bounds__(256)
void tsplit_kernel(const float* __restrict__ W, unsigned short* __restrict__ thi,
                   unsigned short* __restrict__ tlo)
{
    __shared__ float t[32][33];
    const int tx = threadIdx.x & 31, ty = threadIdx.x >> 5;
    const int n0 = blockIdx.x * 32, k0 = blockIdx.y * 32;
    #pragma unroll
    for (int j = 0; j < 4; ++j)
        t[ty + 8 * j][tx] = W[(size_t)(k0 + ty + 8 * j) * D_DIM + n0 + tx];
    __syncthreads();
    #pragma unroll
    for (int j = 0; j < 4; ++j) {
        const float v = t[tx][ty + 8 * j];
        unsigned short h, l; split2(v, h, l);
        const size_t o = (size_t)(n0 + ty + 8 * j) * D_DIM + k0 + tx;
        thi[o] = h; tlo[o] = l;
    }
}

// ---------------------------------------------------------------------------
// MFMA GEMM: out[M,768] = epilogue( (Ahi+Alo) @ (Bhi+Blo)^T' + bias )
//   A: row-major [M][768] bf16 hi/lo. B: Wt [n][k] bf16 hi/lo (pre-transposed).
//   3-term split product: Ahi*Bhi + Ahi*Blo + Alo*Bhi  (fp32 acc, 16x16x32 MFMA)
// MODE 0: h = relu(acc+bias) -> write split bf16 hi/lo
// MODE 1: write float acc + bias + resid
// 128x128 tile, BK=32, 256 thr (4 waves 2x2), wave tile 64x64 (4x4 frags).
// LDS tiles [128 rows][4 x 16B slots], slot XOR-swizzled by ((row>>1)&3)
// applied on BOTH the global source (pre-swizzle) and the ds_read (G21).
// ---------------------------------------------------------------------------
template<int MODE>
__global__ __launch_bounds__(256, 2)
void gemm_mfma(const unsigned short* __restrict__ Ahi, const unsigned short* __restrict__ Alo,
               const unsigned short* __restrict__ Bhi, const unsigned short* __restrict__ Blo,
               const float* __restrict__ bias, const float* __restrict__ resid,
               unsigned short* __restrict__ out_hi, unsigned short* __restrict__ out_lo,
               float* __restrict__ out_f)
{
    __shared__ short8v As_hi[512], As_lo[512], Bs_hi[512], Bs_lo[512]; // 4 x 8KB

    const int tid  = threadIdx.x;
    const int w    = tid >> 6;
    const int lane = tid & 63;
    const int m0   = blockIdx.y * 128;
    const int n0   = blockIdx.x * 128;
    const int wm   = (w >> 1) * 64;     // wave tile origin in block
    const int wn   = (w & 1) * 64;

    // ---- staging source pointers (pre-swizzled global addresses, m173) ----
    const int rr = lane >> 2;          // row-within-1KB-chunk
    const int cc = lane & 3;           // 16B slot
    const int r0 = w * 32 + rr;        // chunk q=0 row (0..127)
    const int r1 = r0 + 16;            // chunk q=1 row
    const int sw0 = (cc ^ ((r0 >> 1) & 3)) * 16;   // swizzled byte-slot in row
    const int sw1 = (cc ^ ((r1 >> 1) & 3)) * 16;
    const size_t aoff0 = (size_t)(m0 + r0) * 1536 + sw0;  // 768*2B row stride
    const size_t aoff1 = (size_t)(m0 + r1) * 1536 + sw1;
    const size_t boff0 = (size_t)(n0 + r0) * 1536 + sw0;
    const size_t boff1 = (size_t)(n0 + r1) * 1536 + sw1;
    const char* pAhi = (const char*)Ahi; const char* pAlo = (const char*)Alo;
    const char* pBhi = (const char*)Bhi; const char* pBlo = (const char*)Blo;
    short8v* dst0[4] = { As_hi + w * 128,      As_lo + w * 128,
                         Bs_hi + w * 128,      Bs_lo + w * 128 };
    short8v* dst1[4] = { As_hi + w * 128 + 64, As_lo + w * 128 + 64,
                         Bs_hi + w * 128 + 64, Bs_lo + w * 128 + 64 };

    // ---- ds_read fragment indices (loop-invariant, swizzle-matched) ----
    const int lc = lane & 15;          // row-in-frag
    const int lk = lane >> 4;          // 16B k-slot
    int ia[4], ib[4];
    #pragma unroll
    for (int m = 0; m < 4; ++m) { const int r = wm + m * 16 + lc; ia[m] = r * 4 + (lk ^ ((r >> 1) & 3)); }
    #pragma unroll
    for (int n = 0; n < 4; ++n) { const int r = wn + n * 16 + lc; ib[n] = r * 4 + (lk ^ ((r >> 1) & 3)); }

    f32x4 acc[4][4];
    #pragma unroll
    for (int m = 0; m < 4; ++m)
        #pragma unroll
        for (int n = 0; n < 4; ++n) acc[m][n] = (f32x4)(0.f);

    for (int kk2 = 0; kk2 < D_DIM * 2; kk2 += 64) {   // 24 K-steps (bytes)
        gld16(pAhi + aoff0 + kk2, dst0[0]);
        gld16(pAhi + aoff1 + kk2, dst1[0]);
        gld16(pAlo + aoff0 + kk2, dst0[1]);
        gld16(pAlo + aoff1 + kk2, dst1[1]);
        gld16(pBhi + boff0 + kk2, dst0[2]);
        gld16(pBhi + boff1 + kk2, dst1[2]);
        gld16(pBlo + boff0 + kk2, dst0[3]);
        gld16(pBlo + boff1 + kk2, dst1[3]);
        __syncthreads();   // drains vmcnt before any wave reads LDS

        short8v ah[4], al[4], bh[4], bl[4];
        #pragma unroll
        for (int m = 0; m < 4; ++m) { ah[m] = As_hi[ia[m]]; al[m] = As_lo[ia[m]]; }
        #pragma unroll
        for (int n = 0; n < 4; ++n) { bh[n] = Bs_hi[ib[n]]; bl[n] = Bs_lo[ib[n]]; }

        #pragma unroll
        for (int m = 0; m < 4; ++m)
            #pragma unroll
            for (int n = 0; n < 4; ++n) {
                acc[m][n] = __builtin_amdgcn_mfma_f32_16x16x32_bf16(ah[m], bh[n], acc[m][n], 0, 0, 0);
                acc[m][n] = __builtin_amdgcn_mfma_f32_16x16x32_bf16(ah[m], bl[n], acc[m][n], 0, 0, 0);
                acc[m][n] = __builtin_amdgcn_mfma_f32_16x16x32_bf16(al[m], bh[n], acc[m][n], 0, 0, 0);
            }
        __syncthreads();   // protect LDS before next stage
    }

    // ---- epilogue: C/D layout col=lane&15, row=(lane>>4)*4+reg (m89) ----
    const int erow = lane >> 4;
    #pragma unroll
    for (int m = 0; m < 4; ++m) {
        #pragma unroll
        for (int n = 0; n < 4; ++n) {
            const int gcol = n0 + wn + n * 16 + lc;
            const float bv = bias[gcol];
            const int grow0 = m0 + wm + m * 16 + erow * 4;
            #pragma unroll
            for (int r = 0; r < 4; ++r) {
                float v = acc[m][n][r] + bv;
                const size_t o = (size_t)(grow0 + r) * D_DIM + gcol;
                if (MODE == 0) {
                    v = fmaxf(v, 0.f);
                    unsigned short h, l; split2(v, h, l);
                    out_hi[o] = h; out_lo[o] = l;
                } else {
                    out_f[o] = v + resid[o];
                }
            }
        }
    }
}

// ---------------------------------------------------------------------------
// LayerNorm in-place over each row of x[M,768]; writes rnorm[m].
// ---------------------------------------------------------------------------
__global__ __launch_bounds__(256)
void ln_kernel(float* __restrict__ x, const float* __restrict__ gamma,
               const float* __restrict__ beta, float* __restrict__ rnorm)
{
    const int wave = threadIdx.x >> 6;
    const int lane = threadIdx.x & 63;
    const int row  = blockIdx.x * 4 + wave;
    float* xr = x + (size_t)row * D_DIM;

    float v[12];
    float sum = 0.f, sumsq = 0.f;
    #pragma unroll
    for (int j = 0; j < 3; ++j) {
        const float4 f = *reinterpret_cast<const float4*>(&xr[j * 256 + lane * 4]);
        v[j * 4 + 0] = f.x; v[j * 4 + 1] = f.y; v[j * 4 + 2] = f.z; v[j * 4 + 3] = f.w;
    }
    #pragma unroll
    for (int e = 0; e < 12; ++e) { sum += v[e]; sumsq = fmaf(v[e], v[e], sumsq); }
    #pragma unroll
    for (int m = 1; m < 64; m <<= 1) {
        sum   += __shfl_xor(sum, m);
        sumsq += __shfl_xor(sumsq, m);
    }
    const float mean = sum * (1.f / 768.f);
    const float var  = sumsq * (1.f / 768.f) - mean * mean;
    const float rstd = 1.f / sqrtf(var + LN_EPS);

    float nsq = 0.f;
    #pragma unroll
    for (int j = 0; j < 3; ++j) {
        const int c = j * 256 + lane * 4;
        const float4 g  = *reinterpret_cast<const float4*>(&gamma[c]);
        const float4 bt = *reinterpret_cast<const float4*>(&beta[c]);
        float4 o;
        o.x = fmaf(g.x * (v[j*4+0] - mean), rstd, bt.x);
        o.y = fmaf(g.y * (v[j*4+1] - mean), rstd, bt.y);
        o.z = fmaf(g.z * (v[j*4+2] - mean), rstd, bt.z);
        o.w = fmaf(g.w * (v[j*4+3] - mean), rstd, bt.w);
        nsq = fmaf(o.x, o.x, nsq); nsq = fmaf(o.y, o.y, nsq);
        nsq = fmaf(o.z, o.z, nsq); nsq = fmaf(o.w, o.w, nsq);
        *reinterpret_cast<float4*>(&xr[c]) = o;
    }
    #pragma unroll
    for (int m = 1; m < 64; m <<= 1) nsq += __shfl_xor(nsq, m);
    if (lane == 0) rnorm[row] = 1.f / fmaxf(sqrtf(nsq), COS_EPS);
}

__global__ void zero_kernel(float* __restrict__ p, int n)
{
    const int i = blockIdx.x * 256 + threadIdx.x;
    if (i < n) p[i] = 0.f;
}

__global__ __launch_bounds__(256)
void colsum_kernel(const float* __restrict__ ff, const float* __restrict__ rnorm,
                   float* __restrict__ s)
{
    const int c = blockIdx.x * 256 + threadIdx.x;
    const int q = blockIdx.y;
    const int b = blockIdx.z;
    const float* fb = ff + (size_t)b * L_DIM * D_DIM;
    const float* rb = rnorm + b * L_DIM;
    float acc = 0.f;
    #pragma unroll 4
    for (int l = q * 128; l < q * 128 + 128; ++l)
        acc = fmaf(fb[(size_t)l * D_DIM + c], rb[l], acc);
    atomicAdd(&s[b * D_DIM + c], acc);
}

__global__ __launch_bounds__(256)
void rowout_kernel(const float* __restrict__ ff, const float* __restrict__ rnorm,
                   const float* __restrict__ s,
                   const float* __restrict__ Wy, const float* __restrict__ by,
                   const float* __restrict__ Wz, const float* __restrict__ bz,
                   float* __restrict__ out1, float* __restrict__ out2,
                   float* __restrict__ aw)
{
    const int wave = threadIdx.x >> 6;
    const int lane = threadIdx.x & 63;
    const int row  = blockIdx.x * 4 + wave;
    const int b    = row >> 9;
    const float* fr = ff + (size_t)row * D_DIM;
    const float* sb = s + b * D_DIM;

    float ds = 0.f;
    float dy[YD] = {0.f, 0.f, 0.f};
    float dz[ZD] = {0.f, 0.f, 0.f, 0.f, 0.f};
    #pragma unroll
    for (int j = 0; j < 3; ++j) {
        const int c = j * 256 + lane * 4;
        const float4 f  = *reinterpret_cast<const float4*>(&fr[c]);
        const float4 sv = *reinterpret_cast<const float4*>(&sb[c]);
        const float fe[4] = {f.x, f.y, f.z, f.w};
        const float se[4] = {sv.x, sv.y, sv.z, sv.w};
        #pragma unroll
        for (int e = 0; e < 4; ++e) {
            const int col = c + e;
            ds = fmaf(fe[e], se[e], ds);
            #pragma unroll
            for (int y = 0; y < YD; ++y) dy[y] = fmaf(fe[e], Wy[col * YD + y], dy[y]);
            #pragma unroll
            for (int z = 0; z < ZD; ++z) dz[z] = fmaf(fe[e], Wz[col * ZD + z], dz[z]);
        }
    }
    #pragma unroll
    for (int m = 1; m < 64; m <<= 1) {
        ds += __shfl_xor(ds, m);
        #pragma unroll
        for (int y = 0; y < YD; ++y) dy[y] += __shfl_xor(dy[y], m);
        #pragma unroll
        for (int z = 0; z < ZD; ++z) dz[z] += __shfl_xor(dz[z], m);
    }
    if (lane == 0) {
        const float a = ds * rnorm[row] * (1.f / (float)L_DIM);
        aw[row] = 1.f / (1.f + expf(a));
        #pragma unroll
        for (int y = 0; y < YD; ++y) out1[(size_t)row * YD + y] = dy[y] + by[y];
        #pragma unroll
        for (int z = 0; z < ZD; ++z) out2[(size_t)row * ZD + z] = dz[z] + bz[z];
    }
}

__global__ __launch_bounds__(512)
void softmax_kernel(const float* __restrict__ aw, float* __restrict__ attn)
{
    __shared__ float red[8];
    const int b = blockIdx.x;
    const int t = threadIdx.x;
    const int wave = t >> 6, lane = t & 63;
    const float v = aw[b * L_DIM + t];

    float mx = v;
    #pragma unroll
    for (int m = 1; m < 64; m <<= 1) mx = fmaxf(mx, __shfl_xor(mx, m));
    if (lane == 0) red[wave] = mx;
    __syncthreads();
    mx = red[0];
    #pragma unroll
    for (int w = 1; w < 8; ++w) mx = fmaxf(mx, red[w]);
    __syncthreads();

    const float e = expf(v - mx);
    float sm = e;
    #pragma unroll
    for (int m = 1; m < 64; m <<= 1) sm += __shfl_xor(sm, m);
    if (lane == 0) red[wave] = sm;
    __syncthreads();
    float tot = 0.f;
    #pragma unroll
    for (int w = 0; w < 8; ++w) tot += red[w];

    attn[b * L_DIM + t] = e / tot;
}

// ---------------------------------------------------------------------------
extern "C" void kernel_launch(void* const* d_in, const int* in_sizes, int n_in,
                              void* d_out, int out_size, void* d_ws, size_t ws_size,
                              hipStream_t stream)
{
    const float* emb   = (const float*)d_in[0];
    const float* W1    = (const float*)d_in[1];
    const float* b1    = (const float*)d_in[2];
    const float* W2    = (const float*)d_in[3];
    const float* b2    = (const float*)d_in[4];
    const float* gamma = (const float*)d_in[5];
    const float* beta  = (const float*)d_in[6];
    const float* Wy    = (const float*)d_in[7];
    const float* by    = (const float*)d_in[8];
    const float* Wz    = (const float*)d_in[9];
    const float* bz    = (const float*)d_in[10];

    float* out = (float*)d_out;
    char*  p   = (char*)d_ws;

    const size_t MD = (size_t)M_DIM * D_DIM;

    unsigned short* h1_hi = (unsigned short*)p;  p += MD * 2;
    unsigned short* h1_lo = (unsigned short*)p;  p += MD * 2;
    // emb-split region aliases xf: emb_hi/lo dead after GEMM1; GEMM2 writes xf here
    float*          xf     = (float*)p;
    unsigned short* emb_hi = (unsigned short*)p;
    unsigned short* emb_lo = emb_hi + MD;        p += MD * 4;
    unsigned short* w1t_hi = (unsigned short*)p; p += (size_t)D_DIM * D_DIM * 2;
    unsigned short* w1t_lo = (unsigned short*)p; p += (size_t)D_DIM * D_DIM * 2;
    unsigned short* w2t_hi = (unsigned short*)p; p += (size_t)D_DIM * D_DIM * 2;
    unsigned short* w2t_lo = (unsigned short*)p; p += (size_t)D_DIM * D_DIM * 2;
    float* rnorm = (float*)p;                    p += (size_t)M_DIM * 4;
    float* awb   = (float*)p;                    p += (size_t)M_DIM * 4;
    float* s     = (float*)p;

    float* out1 = out;
    float* out2 = out + (size_t)M_DIM * YD;
    float* attn = out + (size_t)M_DIM * (YD + ZD);

    split_kernel<<<(int)(MD / 4 / 256), 256, 0, stream>>>(emb, emb_hi, emb_lo, (int)(MD / 4));
    tsplit_kernel<<<dim3(24, 24), 256, 0, stream>>>(W1, w1t_hi, w1t_lo);
    tsplit_kernel<<<dim3(24, 24), 256, 0, stream>>>(W2, w2t_hi, w2t_lo);

    const dim3 gg(D_DIM / 128, M_DIM / 128);     // (6, 256)
    gemm_mfma<0><<<gg, 256, 0, stream>>>(emb_hi, emb_lo, w1t_hi, w1t_lo, b1, nullptr,
                                         h1_hi, h1_lo, nullptr);
    gemm_mfma<1><<<gg, 256, 0, stream>>>(h1_hi, h1_lo, w2t_hi, w2t_lo, b2, emb,
                                         nullptr, nullptr, xf);

    ln_kernel<<<M_DIM / 4, 256, 0, stream>>>(xf, gamma, beta, rnorm);
    zero_kernel<<<(B_DIM * D_DIM + 255) / 256, 256, 0, stream>>>(s, B_DIM * D_DIM);
    colsum_kernel<<<dim3(3, 4, B_DIM), 256, 0, stream>>>(xf, rnorm, s);
    rowout_kernel<<<M_DIM / 4, 256, 0, stream>>>(xf, rnorm, s, Wy, by, Wz, bz,
                                                 out1, out2, awb);
    softmax_kernel<<<B_DIM, 512, 0, stream>>>(awb, attn);
}

// Round 4
// 512.443 us; speedup vs baseline: 2.1596x; 1.1361x over previous
//
#include <hip/hip_runtime.h>
#include <hip/hip_bf16.h>
#include <math.h>

#define D_DIM 768
#define B_DIM 64
#define L_DIM 512
#define M_DIM (B_DIM * L_DIM)   /* 32768 rows */
#define YD 3
#define ZD 5
#define LN_EPS 1e-5f
#define COS_EPS 1e-8f

typedef short short8v __attribute__((ext_vector_type(8)));
typedef float f32x4  __attribute__((ext_vector_type(4)));

// ---------------------------------------------------------------------------
// bf16 helpers (RNE), split x = hi + lo with hi,lo bf16; |err| <= 2^-17 |x|
// ---------------------------------------------------------------------------
__device__ __forceinline__ unsigned short f2bf(float f) {
    unsigned u = __builtin_bit_cast(unsigned, f);
    u = (u + 0x7fffu + ((u >> 16) & 1u)) >> 16;
    return (unsigned short)u;
}
__device__ __forceinline__ float bf2f(unsigned short h) {
    unsigned u = ((unsigned)h) << 16;
    return __builtin_bit_cast(float, u);
}
__device__ __forceinline__ void split2(float v, unsigned short& h, unsigned short& l) {
    h = f2bf(v);
    l = f2bf(v - bf2f(h));
}

// async global->LDS, 16B per lane, wave-uniform LDS base + lane*16
__device__ __forceinline__ void gld16(const void* g, void* l) {
    __builtin_amdgcn_global_load_lds(
        (const __attribute__((address_space(1))) void*)g,
        (__attribute__((address_space(3))) void*)l, 16, 0, 0);
}

// ---------------------------------------------------------------------------
// split emb -> hi/lo bf16 (vectorized, 4 elems/thread)
// ---------------------------------------------------------------------------
__global__ __launch_bounds__(256)
void split_kernel(const float* __restrict__ in, unsigned short* __restrict__ hi,
                  unsigned short* __restrict__ lo, int n4)
{
    const int i = blockIdx.x * 256 + threadIdx.x;
    if (i >= n4) return;
    const float4 v = reinterpret_cast<const float4*>(in)[i];
    ushort4 h, l;
    split2(v.x, h.x, l.x); split2(v.y, h.y, l.y);
    split2(v.z, h.z, l.z); split2(v.w, h.w, l.w);
    reinterpret_cast<ushort4*>(hi)[i] = h;
    reinterpret_cast<ushort4*>(lo)[i] = l;
}

// ---------------------------------------------------------------------------
// W[768][768] -> Wt_hi/Wt_lo[n][k] (transposed, split). 32x32 LDS tiles.
// ---------------------------------------------------------------------------
__global__ __launch_bounds__(256)
void tsplit_kernel(const float* __restrict__ W, unsigned short* __restrict__ thi,
                   unsigned short* __restrict__ tlo)
{
    __shared__ float t[32][33];
    const int tx = threadIdx.x & 31, ty = threadIdx.x >> 5;
    const int n0 = blockIdx.x * 32, k0 = blockIdx.y * 32;
    #pragma unroll
    for (int j = 0; j < 4; ++j)
        t[ty + 8 * j][tx] = W[(size_t)(k0 + ty + 8 * j) * D_DIM + n0 + tx];
    __syncthreads();
    #pragma unroll
    for (int j = 0; j < 4; ++j) {
        const float v = t[tx][ty + 8 * j];
        unsigned short h, l; split2(v, h, l);
        const size_t o = (size_t)(n0 + ty + 8 * j) * D_DIM + k0 + tx;
        thi[o] = h; tlo[o] = l;
    }
}

// ---------------------------------------------------------------------------
// MFMA GEMM: out[M,768] = epilogue( (Ahi+Alo) @ (Bhi+Blo)^T' + bias )
//   3-term split product: Ahi*Bhi + Ahi*Blo + Alo*Bhi  (fp32 acc, 16x16x32)
// MODE 0: h = relu(acc+bias) -> write split bf16 hi/lo
// MODE 1: write float acc + bias + resid
// 128x128 tile, BK=32, 256 thr (4 waves 2x2), wave tile 64x64 (4x4 frags).
// XCD-aware bijective block swizzle (T1): the 6 n-blocks sharing an A panel
// become consecutive on one XCD -> A panel L2-resident (nwg=1536, %8==0).
// LDS slot XOR-swizzle applied on BOTH global source and ds_read (G21).
// ---------------------------------------------------------------------------
template<int MODE>
__global__ __launch_bounds__(256, 2)
void gemm_mfma(const unsigned short* __restrict__ Ahi, const unsigned short* __restrict__ Alo,
               const unsigned short* __restrict__ Bhi, const unsigned short* __restrict__ Blo,
               const float* __restrict__ bias, const float* __restrict__ resid,
               unsigned short* __restrict__ out_hi, unsigned short* __restrict__ out_lo,
               float* __restrict__ out_f)
{
    __shared__ short8v As_hi[512], As_lo[512], Bs_hi[512], Bs_lo[512]; // 4 x 8KB

    // ---- XCD-aware swizzle: lin -> lid, then (bx,by) ----
    const int lin = blockIdx.y * gridDim.x + blockIdx.x;     // hw linear id
    const int cpx = (gridDim.x * gridDim.y) >> 3;            // 192
    const int lid = (lin & 7) * cpx + (lin >> 3);
    const int bx  = lid % 6;
    const int by  = lid / 6;

    const int tid  = threadIdx.x;
    const int w    = tid >> 6;
    const int lane = tid & 63;
    const int m0   = by * 128;
    const int n0   = bx * 128;
    const int wm   = (w >> 1) * 64;     // wave tile origin in block
    const int wn   = (w & 1) * 64;

    // ---- staging source pointers (pre-swizzled global addresses, m173) ----
    const int rr = lane >> 2;          // row-within-1KB-chunk
    const int cc = lane & 3;           // 16B slot
    const int r0 = w * 32 + rr;        // chunk q=0 row (0..127)
    const int r1 = r0 + 16;            // chunk q=1 row
    const int sw0 = (cc ^ ((r0 >> 1) & 3)) * 16;   // swizzled byte-slot in row
    const int sw1 = (cc ^ ((r1 >> 1) & 3)) * 16;
    const size_t aoff0 = (size_t)(m0 + r0) * 1536 + sw0;  // 768*2B row stride
    const size_t aoff1 = (size_t)(m0 + r1) * 1536 + sw1;
    const size_t boff0 = (size_t)(n0 + r0) * 1536 + sw0;
    const size_t boff1 = (size_t)(n0 + r1) * 1536 + sw1;
    const char* pAhi = (const char*)Ahi; const char* pAlo = (const char*)Alo;
    const char* pBhi = (const char*)Bhi; const char* pBlo = (const char*)Blo;
    short8v* dst0[4] = { As_hi + w * 128,      As_lo + w * 128,
                         Bs_hi + w * 128,      Bs_lo + w * 128 };
    short8v* dst1[4] = { As_hi + w * 128 + 64, As_lo + w * 128 + 64,
                         Bs_hi + w * 128 + 64, Bs_lo + w * 128 + 64 };

    // ---- ds_read fragment indices (loop-invariant, swizzle-matched) ----
    const int lc = lane & 15;          // row-in-frag
    const int lk = lane >> 4;          // 16B k-slot
    int ia[4], ib[4];
    #pragma unroll
    for (int m = 0; m < 4; ++m) { const int r = wm + m * 16 + lc; ia[m] = r * 4 + (lk ^ ((r >> 1) & 3)); }
    #pragma unroll
    for (int n = 0; n < 4; ++n) { const int r = wn + n * 16 + lc; ib[n] = r * 4 + (lk ^ ((r >> 1) & 3)); }

    f32x4 acc[4][4];
    #pragma unroll
    for (int m = 0; m < 4; ++m)
        #pragma unroll
        for (int n = 0; n < 4; ++n) acc[m][n] = (f32x4)(0.f);

    for (int kk2 = 0; kk2 < D_DIM * 2; kk2 += 64) {   // 24 K-steps (bytes)
        gld16(pAhi + aoff0 + kk2, dst0[0]);
        gld16(pAhi + aoff1 + kk2, dst1[0]);
        gld16(pAlo + aoff0 + kk2, dst0[1]);
        gld16(pAlo + aoff1 + kk2, dst1[1]);
        gld16(pBhi + boff0 + kk2, dst0[2]);
        gld16(pBhi + boff1 + kk2, dst1[2]);
        gld16(pBlo + boff0 + kk2, dst0[3]);
        gld16(pBlo + boff1 + kk2, dst1[3]);
        __syncthreads();   // drains vmcnt before any wave reads LDS

        short8v ah[4], al[4], bh[4], bl[4];
        #pragma unroll
        for (int m = 0; m < 4; ++m) { ah[m] = As_hi[ia[m]]; al[m] = As_lo[ia[m]]; }
        #pragma unroll
        for (int n = 0; n < 4; ++n) { bh[n] = Bs_hi[ib[n]]; bl[n] = Bs_lo[ib[n]]; }

        #pragma unroll
        for (int m = 0; m < 4; ++m)
            #pragma unroll
            for (int n = 0; n < 4; ++n) {
                acc[m][n] = __builtin_amdgcn_mfma_f32_16x16x32_bf16(ah[m], bh[n], acc[m][n], 0, 0, 0);
                acc[m][n] = __builtin_amdgcn_mfma_f32_16x16x32_bf16(ah[m], bl[n], acc[m][n], 0, 0, 0);
                acc[m][n] = __builtin_amdgcn_mfma_f32_16x16x32_bf16(al[m], bh[n], acc[m][n], 0, 0, 0);
            }
        __syncthreads();   // protect LDS before next stage
    }

    // ---- epilogue: C/D layout col=lane&15, row=(lane>>4)*4+reg (m89) ----
    const int erow = lane >> 4;
    #pragma unroll
    for (int m = 0; m < 4; ++m) {
        #pragma unroll
        for (int n = 0; n < 4; ++n) {
            const int gcol = n0 + wn + n * 16 + lc;
            const float bv = bias[gcol];
            const int grow0 = m0 + wm + m * 16 + erow * 4;
            #pragma unroll
            for (int r = 0; r < 4; ++r) {
                float v = acc[m][n][r] + bv;
                const size_t o = (size_t)(grow0 + r) * D_DIM + gcol;
                if (MODE == 0) {
                    v = fmaxf(v, 0.f);
                    unsigned short h, l; split2(v, h, l);
                    out_hi[o] = h; out_lo[o] = l;
                } else {
                    out_f[o] = v + resid[o];
                }
            }
        }
    }
}

// ---------------------------------------------------------------------------
// LayerNorm: reads x[M,768] fp32, writes ff as bf16 + rnorm[m].
// One wave per row, 4 rows per block.
// ---------------------------------------------------------------------------
__global__ __launch_bounds__(256)
void ln_kernel(const float* __restrict__ x, const float* __restrict__ gamma,
               const float* __restrict__ beta, unsigned short* __restrict__ ffb,
               float* __restrict__ rnorm)
{
    const int wave = threadIdx.x >> 6;
    const int lane = threadIdx.x & 63;
    const int row  = blockIdx.x * 4 + wave;
    const float* xr = x + (size_t)row * D_DIM;
    unsigned short* fr = ffb + (size_t)row * D_DIM;

    float v[12];
    float sum = 0.f, sumsq = 0.f;
    #pragma unroll
    for (int j = 0; j < 3; ++j) {
        const float4 f = *reinterpret_cast<const float4*>(&xr[j * 256 + lane * 4]);
        v[j * 4 + 0] = f.x; v[j * 4 + 1] = f.y; v[j * 4 + 2] = f.z; v[j * 4 + 3] = f.w;
    }
    #pragma unroll
    for (int e = 0; e < 12; ++e) { sum += v[e]; sumsq = fmaf(v[e], v[e], sumsq); }
    #pragma unroll
    for (int m = 1; m < 64; m <<= 1) {
        sum   += __shfl_xor(sum, m);
        sumsq += __shfl_xor(sumsq, m);
    }
    const float mean = sum * (1.f / 768.f);
    const float var  = sumsq * (1.f / 768.f) - mean * mean;
    const float rstd = 1.f / sqrtf(var + LN_EPS);

    float nsq = 0.f;
    #pragma unroll
    for (int j = 0; j < 3; ++j) {
        const int c = j * 256 + lane * 4;
        const float4 g  = *reinterpret_cast<const float4*>(&gamma[c]);
        const float4 bt = *reinterpret_cast<const float4*>(&beta[c]);
        float4 o;
        o.x = fmaf(g.x * (v[j*4+0] - mean), rstd, bt.x);
        o.y = fmaf(g.y * (v[j*4+1] - mean), rstd, bt.y);
        o.z = fmaf(g.z * (v[j*4+2] - mean), rstd, bt.z);
        o.w = fmaf(g.w * (v[j*4+3] - mean), rstd, bt.w);
        nsq = fmaf(o.x, o.x, nsq); nsq = fmaf(o.y, o.y, nsq);
        nsq = fmaf(o.z, o.z, nsq); nsq = fmaf(o.w, o.w, nsq);
        ushort4 ob;
        ob.x = f2bf(o.x); ob.y = f2bf(o.y); ob.z = f2bf(o.z); ob.w = f2bf(o.w);
        *reinterpret_cast<ushort4*>(&fr[c]) = ob;
    }
    #pragma unroll
    for (int m = 1; m < 64; m <<= 1) nsq += __shfl_xor(nsq, m);
    if (lane == 0) rnorm[row] = 1.f / fmaxf(sqrtf(nsq), COS_EPS);
}

__global__ void zero_kernel(float* __restrict__ p, int n)
{
    const int i = blockIdx.x * 256 + threadIdx.x;
    if (i < n) p[i] = 0.f;
}

// ---------------------------------------------------------------------------
// s[b][d] = sum_l ff[b][l][d] * rnorm[b][l]  (bf16 ff; partial per L-quarter)
// ---------------------------------------------------------------------------
__global__ __launch_bounds__(256)
void colsum_kernel(const unsigned short* __restrict__ ffb, const float* __restrict__ rnorm,
                   float* __restrict__ s)
{
    const int c = blockIdx.x * 256 + threadIdx.x;
    const int q = blockIdx.y;
    const int b = blockIdx.z;
    const unsigned short* fb = ffb + (size_t)b * L_DIM * D_DIM;
    const float* rb = rnorm + b * L_DIM;
    float acc = 0.f;
    #pragma unroll 4
    for (int l = q * 128; l < q * 128 + 128; ++l)
        acc = fmaf(bf2f(fb[(size_t)l * D_DIM + c]), rb[l], acc);
    atomicAdd(&s[b * D_DIM + c], acc);
}

// ---------------------------------------------------------------------------
// Per-row epilogue: out1 = ff@Wy + by, out2 = ff@Wz + bz,
// aw_raw = 1/(1+exp(ff.s * rnorm / L)). One wave per row. bf16 ff loads.
// ---------------------------------------------------------------------------
__global__ __launch_bounds__(256)
void rowout_kernel(const unsigned short* __restrict__ ffb, const float* __restrict__ rnorm,
                   const float* __restrict__ s,
                   const float* __restrict__ Wy, const float* __restrict__ by,
                   const float* __restrict__ Wz, const float* __restrict__ bz,
                   float* __restrict__ out1, float* __restrict__ out2,
                   float* __restrict__ aw)
{
    const int wave = threadIdx.x >> 6;
    const int lane = threadIdx.x & 63;
    const int row  = blockIdx.x * 4 + wave;
    const int b    = row >> 9;
    const unsigned short* fr = ffb + (size_t)row * D_DIM;
    const float* sb = s + b * D_DIM;

    float ds = 0.f;
    float dy[YD] = {0.f, 0.f, 0.f};
    float dz[ZD] = {0.f, 0.f, 0.f, 0.f, 0.f};
    #pragma unroll
    for (int j = 0; j < 3; ++j) {
        const int c = j * 256 + lane * 4;
        const ushort4 fb4 = *reinterpret_cast<const ushort4*>(&fr[c]);
        const float4 sv = *reinterpret_cast<const float4*>(&sb[c]);
        const float fe[4] = {bf2f(fb4.x), bf2f(fb4.y), bf2f(fb4.z), bf2f(fb4.w)};
        const float se[4] = {sv.x, sv.y, sv.z, sv.w};
        #pragma unroll
        for (int e = 0; e < 4; ++e) {
            const int col = c + e;
            ds = fmaf(fe[e], se[e], ds);
            #pragma unroll
            for (int y = 0; y < YD; ++y) dy[y] = fmaf(fe[e], Wy[col * YD + y], dy[y]);
            #pragma unroll
            for (int z = 0; z < ZD; ++z) dz[z] = fmaf(fe[e], Wz[col * ZD + z], dz[z]);
        }
    }
    #pragma unroll
    for (int m = 1; m < 64; m <<= 1) {
        ds += __shfl_xor(ds, m);
        #pragma unroll
        for (int y = 0; y < YD; ++y) dy[y] += __shfl_xor(dy[y], m);
        #pragma unroll
        for (int z = 0; z < ZD; ++z) dz[z] += __shfl_xor(dz[z], m);
    }
    if (lane == 0) {
        const float a = ds * rnorm[row] * (1.f / (float)L_DIM);
        aw[row] = 1.f / (1.f + expf(a));
        #pragma unroll
        for (int y = 0; y < YD; ++y) out1[(size_t)row * YD + y] = dy[y] + by[y];
        #pragma unroll
        for (int z = 0; z < ZD; ++z) out2[(size_t)row * ZD + z] = dz[z] + bz[z];
    }
}

__global__ __launch_bounds__(512)
void softmax_kernel(const float* __restrict__ aw, float* __restrict__ attn)
{
    __shared__ float red[8];
    const int b = blockIdx.x;
    const int t = threadIdx.x;
    const int wave = t >> 6, lane = t & 63;
    const float v = aw[b * L_DIM + t];

    float mx = v;
    #pragma unroll
    for (int m = 1; m < 64; m <<= 1) mx = fmaxf(mx, __shfl_xor(mx, m));
    if (lane == 0) red[wave] = mx;
    __syncthreads();
    mx = red[0];
    #pragma unroll
    for (int w = 1; w < 8; ++w) mx = fmaxf(mx, red[w]);
    __syncthreads();

    const float e = expf(v - mx);
    float sm = e;
    #pragma unroll
    for (int m = 1; m < 64; m <<= 1) sm += __shfl_xor(sm, m);
    if (lane == 0) red[wave] = sm;
    __syncthreads();
    float tot = 0.f;
    #pragma unroll
    for (int w = 0; w < 8; ++w) tot += red[w];

    attn[b * L_DIM + t] = e / tot;
}

// ---------------------------------------------------------------------------
extern "C" void kernel_launch(void* const* d_in, const int* in_sizes, int n_in,
                              void* d_out, int out_size, void* d_ws, size_t ws_size,
                              hipStream_t stream)
{
    const float* emb   = (const float*)d_in[0];
    const float* W1    = (const float*)d_in[1];
    const float* b1    = (const float*)d_in[2];
    const float* W2    = (const float*)d_in[3];
    const float* b2    = (const float*)d_in[4];
    const float* gamma = (const float*)d_in[5];
    const float* beta  = (const float*)d_in[6];
    const float* Wy    = (const float*)d_in[7];
    const float* by    = (const float*)d_in[8];
    const float* Wz    = (const float*)d_in[9];
    const float* bz    = (const float*)d_in[10];

    float* out = (float*)d_out;
    char*  p   = (char*)d_ws;

    const size_t MD = (size_t)M_DIM * D_DIM;

    unsigned short* h1_hi = (unsigned short*)p;  p += MD * 2;
    unsigned short* h1_lo = (unsigned short*)p;  p += MD * 2;
    // emb-split region aliases xf: emb_hi/lo dead after GEMM1; GEMM2 writes xf here
    float*          xf     = (float*)p;
    unsigned short* emb_hi = (unsigned short*)p;
    unsigned short* emb_lo = emb_hi + MD;        p += MD * 4;
    unsigned short* w1t_hi = (unsigned short*)p; p += (size_t)D_DIM * D_DIM * 2;
    unsigned short* w1t_lo = (unsigned short*)p; p += (size_t)D_DIM * D_DIM * 2;
    unsigned short* w2t_hi = (unsigned short*)p; p += (size_t)D_DIM * D_DIM * 2;
    unsigned short* w2t_lo = (unsigned short*)p; p += (size_t)D_DIM * D_DIM * 2;
    float* rnorm = (float*)p;                    p += (size_t)M_DIM * 4;
    float* awb   = (float*)p;                    p += (size_t)M_DIM * 4;
    float* s     = (float*)p;

    // ff (bf16) aliases h1_hi: h1 hi/lo are dead after GEMM2 completes.
    unsigned short* ffb = h1_hi;

    float* out1 = out;
    float* out2 = out + (size_t)M_DIM * YD;
    float* attn = out + (size_t)M_DIM * (YD + ZD);

    split_kernel<<<(int)(MD / 4 / 256), 256, 0, stream>>>(emb, emb_hi, emb_lo, (int)(MD / 4));
    tsplit_kernel<<<dim3(24, 24), 256, 0, stream>>>(W1, w1t_hi, w1t_lo);
    tsplit_kernel<<<dim3(24, 24), 256, 0, stream>>>(W2, w2t_hi, w2t_lo);

    const dim3 gg(D_DIM / 128, M_DIM / 128);     // (6, 256) = 1536 wgs, %8==0
    gemm_mfma<0><<<gg, 256, 0, stream>>>(emb_hi, emb_lo, w1t_hi, w1t_lo, b1, nullptr,
                                         h1_hi, h1_lo, nullptr);
    gemm_mfma<1><<<gg, 256, 0, stream>>>(h1_hi, h1_lo, w2t_hi, w2t_lo, b2, emb,
                                         nullptr, nullptr, xf);

    ln_kernel<<<M_DIM / 4, 256, 0, stream>>>(xf, gamma, beta, ffb, rnorm);
    zero_kernel<<<(B_DIM * D_DIM + 255) / 256, 256, 0, stream>>>(s, B_DIM * D_DIM);
    colsum_kernel<<<dim3(3, 4, B_DIM), 256, 0, stream>>>(ffb, rnorm, s);
    rowout_kernel<<<M_DIM / 4, 256, 0, stream>>>(ffb, rnorm, s, Wy, by, Wz, bz,
                                                 out1, out2, awb);
    softmax_kernel<<<B_DIM, 512, 0, stream>>>(awb, attn);
}